// Round 4
// baseline (2801.438 us; speedup 1.0000x reference)
//
#include <hip/hip_runtime.h>

#define N_NODES 100000
#define N_PAD   100352        // 1568*64
#define N_EDGES 3200000
#define IN_DIM  128
#define HID     64
#define N_GRAPHS 256
#define NB      1568          // buckets of 64 dest nodes each
#define NBLK    256           // hist/scatter blocks
#define EPB     (N_EDGES / NBLK)   // 12500
#define ASTR    68            // LDS accumulator row stride (bank stagger)

// ---------- phase 1: per-block bucket histogram (LDS only, no global atomics) ----------
__global__ __launch_bounds__(256) void bhist_kernel(const int* __restrict__ col,
                                                    int* __restrict__ H) {
    __shared__ int h[NB];
    for (int i = threadIdx.x; i < NB; i += 256) h[i] = 0;
    __syncthreads();
    int base = blockIdx.x * EPB;
    for (int j = threadIdx.x; j < EPB; j += 256) atomicAdd(&h[col[base + j] >> 6], 1);
    __syncthreads();
    for (int i = threadIdx.x; i < NB; i += 256) H[i * NBLK + blockIdx.x] = h[i];
}

// ---------- phase 2: exclusive scan of H (NB*NBLK, bucket-major) ----------
__global__ __launch_bounds__(256) void scan1_kernel(int* H, int* __restrict__ bsum) {
    __shared__ int s[256];
    int i = blockIdx.x * 256 + threadIdx.x;
    int v = H[i];
    s[threadIdx.x] = v;
    __syncthreads();
    #pragma unroll
    for (int off = 1; off < 256; off <<= 1) {
        int t = (threadIdx.x >= off) ? s[threadIdx.x - off] : 0;
        __syncthreads();
        s[threadIdx.x] += t;
        __syncthreads();
    }
    H[i] = s[threadIdx.x] - v;                  // exclusive within bucket
    if (threadIdx.x == 255) bsum[blockIdx.x] = s[255];   // bucket total
}

__global__ __launch_bounds__(256) void scan2_kernel(const int* __restrict__ bsum,
                                                    int* __restrict__ boff) {
    __shared__ int s[256];
    __shared__ int carry;
    if (threadIdx.x == 0) carry = 0;
    __syncthreads();
    for (int c = 0; c < (NB + 255) / 256; ++c) {
        int i = c * 256 + threadIdx.x;
        int v = (i < NB) ? bsum[i] : 0;
        s[threadIdx.x] = v;
        __syncthreads();
        #pragma unroll
        for (int off = 1; off < 256; off <<= 1) {
            int t = (threadIdx.x >= off) ? s[threadIdx.x - off] : 0;
            __syncthreads();
            s[threadIdx.x] += t;
            __syncthreads();
        }
        if (i < NB) boff[i] = s[threadIdx.x] - v + carry;   // bucket start offsets
        __syncthreads();
        if (threadIdx.x == 0) carry += s[255];
        __syncthreads();
    }
}

__global__ __launch_bounds__(256) void scan3_kernel(int* H, const int* __restrict__ boff) {
    int i = blockIdx.x * 256 + threadIdx.x;   // grid NB; blockIdx.x == bucket
    H[i] += boff[blockIdx.x];
}

// ---------- phase 3: scatter records; cursors live in LDS (no global atomics) ----------
// each (block,bucket) owns a private contiguous range -> writes are run-sequential
__global__ __launch_bounds__(256) void bscatter_kernel(const int* __restrict__ row,
                                                       const int* __restrict__ col,
                                                       const float* __restrict__ ew,
                                                       const int* __restrict__ H,
                                                       int2* __restrict__ recs) {
    __shared__ int cur[NB];
    for (int i = threadIdx.x; i < NB; i += 256) cur[i] = H[i * NBLK + blockIdx.x];
    __syncthreads();
    int base = blockIdx.x * EPB;
    for (int j = threadIdx.x; j < EPB; j += 256) {
        int e = base + j;
        int c = col[e];
        int pos = atomicAdd(&cur[c >> 6], 1);
        recs[pos] = make_int2(row[e] | ((c & 63) << 17), __float_as_int(ew[e]));
    }
}

// ---------- deg/dis from bucket lists: dis = rsqrt(1 + sum ew) ----------
__global__ __launch_bounds__(256) void degdis_kernel(const int2* __restrict__ recs,
                                                     const int* __restrict__ boff,
                                                     float* __restrict__ dis) {
    __shared__ float acc[64];
    int b = blockIdx.x;
    if (threadIdx.x < 64) acc[threadIdx.x] = 0.f;
    __syncthreads();
    int s = boff[b], e = (b + 1 < NB) ? boff[b + 1] : N_EDGES;
    for (int j = s + threadIdx.x; j < e; j += 256) {
        int2 r = recs[j];
        atomicAdd(&acc[(r.x >> 17) & 63], __int_as_float(r.y));
    }
    __syncthreads();
    if (threadIdx.x < 64) {
        int n = b * 64 + threadIdx.x;
        if (n < N_NODES) dis[n] = 1.0f / sqrtf(fmaxf(1.0f + acc[threadIdx.x], 1e-30f));
    }
}

// ---------- layer 1 GEMM: xl = x @ W1 ----------
__global__ __launch_bounds__(256) void gemm1_kernel(const float* __restrict__ x,
                                                    const float* __restrict__ W1,
                                                    float* __restrict__ xl) {
    __shared__ float sW[IN_DIM * HID];   // 32 KB
    __shared__ float sx[4][IN_DIM];
    int tid = threadIdx.x;
    const float4* W4  = (const float4*)W1;
    float4*       sW4 = (float4*)sW;
    #pragma unroll
    for (int i = 0; i < 8; ++i) sW4[tid + 256 * i] = W4[tid + 256 * i];
    int r0 = blockIdx.x * 4;
    const float4* x4  = (const float4*)(x + (size_t)r0 * IN_DIM);
    float4*       sx4 = (float4*)&sx[0][0];
    if (tid < 128) sx4[tid] = x4[tid];
    __syncthreads();
    int lr = tid >> 6, c = tid & 63;
    float acc = 0.f;
    #pragma unroll 8
    for (int k = 0; k < IN_DIM; ++k) acc += sx[lr][k] * sW[k * HID + c];
    xl[(size_t)(r0 + lr) * HID + c] = acc;
}

// ---------- bucketed aggregation: agg[n] = xl[n]*dis[n]^2 + sum edges ----------
// one block per bucket; 4 edges in flight per wave (16 lanes x float4 each);
// LDS fp32 accumulator with stride-68 stagger to avoid 4-way bank aliasing
__global__ __launch_bounds__(256) void bagg_kernel(const int2* __restrict__ recs,
                                                   const int* __restrict__ boff,
                                                   const float* __restrict__ dis,
                                                   const float* __restrict__ xl,
                                                   float* __restrict__ agg) {
    __shared__ float acc[64 * ASTR];   // 17.4 KB
    __shared__ float sdis[64];
    int b = blockIdx.x;
    int tid = threadIdx.x;
    for (int i = tid; i < 64 * ASTR; i += 256) acc[i] = 0.f;
    if (tid < 64) sdis[tid] = dis[b * 64 + tid];   // within N_PAD alloc
    int start = boff[b];
    int end = (b + 1 < NB) ? boff[b + 1] : N_EDGES;
    __syncthreads();
    int lane = tid & 63, wv = tid >> 6;
    int q = lane >> 4, c0 = (lane & 15) << 2;
    for (int j0 = start + wv * 4; j0 < end; j0 += 16) {
        int2 rv = make_int2(0, 0);
        if (lane < 4 && j0 + lane < end) rv = recs[j0 + lane];
        int pk = __shfl(rv.x, q, 64);
        int eb = __shfl(rv.y, q, 64);
        if (j0 + q < end) {
            int r  = pk & 0x1FFFF;
            int cl = (pk >> 17) & 63;
            float w = dis[r] * __int_as_float(eb) * sdis[cl];
            const float4 xv = *(const float4*)(xl + (size_t)r * HID + c0);
            float* a = &acc[cl * ASTR + c0];
            atomicAdd(a + 0, xv.x * w);
            atomicAdd(a + 1, xv.y * w);
            atomicAdd(a + 2, xv.z * w);
            atomicAdd(a + 3, xv.w * w);
        }
    }
    __syncthreads();
    #pragma unroll
    for (int k = 0; k < 16; ++k) {
        int nl = k * 4 + wv;
        int n = b * 64 + nl;
        if (n < N_NODES) {
            float d = sdis[nl];
            float v = acc[nl * ASTR + lane] + xl[(size_t)n * HID + lane] * d * d;
            agg[(size_t)n * HID + lane] = v;
        }
    }
}

// ---------- layer 2 GEMM: xl2 = relu(agg1 + b1) @ W2 ----------
__global__ __launch_bounds__(256) void gemm2_kernel(const float* __restrict__ agg1,
                                                    const float* __restrict__ W2,
                                                    const float* __restrict__ b1,
                                                    float* __restrict__ xl2) {
    __shared__ float sW[HID * HID];
    __shared__ float sh[4][HID];
    int tid = threadIdx.x;
    const float4* W4  = (const float4*)W2;
    float4*       sW4 = (float4*)sW;
    #pragma unroll
    for (int i = 0; i < 4; ++i) sW4[tid + 256 * i] = W4[tid + 256 * i];
    int r0 = blockIdx.x * 4;
    int lr = tid >> 6, c = tid & 63;
    float v = agg1[(size_t)(r0 + lr) * HID + c] + b1[c];
    sh[lr][c] = v > 0.f ? v : 0.f;
    __syncthreads();
    float acc = 0.f;
    #pragma unroll 8
    for (int k = 0; k < HID; ++k) acc += sh[lr][k] * sW[k * HID + c];
    xl2[(size_t)(r0 + lr) * HID + c] = acc;
}

// ---------- pooling + head ----------
__global__ __launch_bounds__(256) void pool_head_kernel(const float* __restrict__ agg2,
                                                        const float* __restrict__ b2,
                                                        const int* __restrict__ batch,
                                                        const float* __restrict__ Wc,
                                                        const float* __restrict__ bc,
                                                        float* __restrict__ out) {
    int g = blockIdx.x;
    int lo = 0, hi = N_NODES;
    while (lo < hi) { int m = (lo + hi) >> 1; if (batch[m] < g) lo = m + 1; else hi = m; }
    int start = lo;
    hi = N_NODES;
    while (lo < hi) { int m = (lo + hi) >> 1; if (batch[m] < g + 1) lo = m + 1; else hi = m; }
    int end = lo;
    int w = threadIdx.x >> 6, lane = threadIdx.x & 63;
    float bb = b2[lane];
    float acc = 0.f;
    for (int i = start + w; i < end; i += 4) {
        float v = agg2[(size_t)i * HID + lane] + bb;
        acc += v > 0.f ? v : 0.f;
    }
    __shared__ float s[4][HID];
    s[w][lane] = acc;
    __syncthreads();
    if (w == 0) {
        float p = s[0][lane] + s[1][lane] + s[2][lane] + s[3][lane];
        float cntf = (float)(end - start);
        p = p / fmaxf(cntf, 1.0f) * Wc[lane];
        #pragma unroll
        for (int o = 32; o > 0; o >>= 1) p += __shfl_down(p, o, 64);
        if (lane == 0) out[g] = p + bc[0];
    }
}

extern "C" void kernel_launch(void* const* d_in, const int* in_sizes, int n_in,
                              void* d_out, int out_size, void* d_ws, size_t ws_size,
                              hipStream_t stream) {
    const float* x     = (const float*)d_in[0];
    const int*   ei    = (const int*)  d_in[1];
    const float* ew    = (const float*)d_in[2];
    const int*   batch = (const int*)  d_in[3];
    const float* W1    = (const float*)d_in[4];
    const float* b1    = (const float*)d_in[5];
    const float* W2    = (const float*)d_in[6];
    const float* b2    = (const float*)d_in[7];
    const float* Wc    = (const float*)d_in[8];
    const float* bc    = (const float*)d_in[9];
    float* out = (float*)d_out;

    const int* row = ei;
    const int* col = ei + N_EDGES;

    // workspace (~77.3 MB): bufA | bufB | recs | dis | bsum | boff ; H overlays bufB
    float* bufA = (float*)d_ws;                          // N*HID
    float* bufB = bufA + (size_t)N_NODES * HID;          // N*HID
    int2*  recs = (int2*)(bufB + (size_t)N_NODES * HID); // E int2
    float* dis  = (float*)(recs + N_EDGES);              // N_PAD
    int*   bsum = (int*)(dis + N_PAD);                   // 2048
    int*   boff = bsum + 2048;                           // 2048
    int*   H    = (int*)bufB;                            // NB*NBLK, dead before bufB written

    bhist_kernel   <<<NBLK, 256, 0, stream>>>(col, H);
    scan1_kernel   <<<NB,   256, 0, stream>>>(H, bsum);
    scan2_kernel   <<<1,    256, 0, stream>>>(bsum, boff);
    scan3_kernel   <<<NB,   256, 0, stream>>>(H, boff);
    bscatter_kernel<<<NBLK, 256, 0, stream>>>(row, col, ew, H, recs);
    degdis_kernel  <<<NB,   256, 0, stream>>>(recs, boff, dis);
    gemm1_kernel   <<<N_NODES / 4, 256, 0, stream>>>(x, W1, bufA);
    bagg_kernel    <<<NB,   256, 0, stream>>>(recs, boff, dis, bufA, bufB);
    gemm2_kernel   <<<N_NODES / 4, 256, 0, stream>>>(bufB, W2, b1, bufA);
    bagg_kernel    <<<NB,   256, 0, stream>>>(recs, boff, dis, bufA, bufB);
    pool_head_kernel<<<N_GRAPHS, 256, 0, stream>>>(bufB, b2, batch, Wc, bc, out);
}

// Round 5
// 658.762 us; speedup vs baseline: 4.2526x; 4.2526x over previous
//
#include <hip/hip_runtime.h>

#define N_NODES 100000
#define N_PAD   100352        // 1568*64
#define N_EDGES 3200000
#define IN_DIM  128
#define HID     64
#define N_GRAPHS 256
#define NB      1568          // buckets of 64 dest nodes each
#define NBLK    256           // hist/scatter blocks
#define EPB     (N_EDGES / NBLK)   // 12500

// ---------- phase 1: per-block bucket histogram (LDS only, no global atomics) ----------
__global__ __launch_bounds__(256) void bhist_kernel(const int* __restrict__ col,
                                                    int* __restrict__ H) {
    __shared__ int h[NB];
    for (int i = threadIdx.x; i < NB; i += 256) h[i] = 0;
    __syncthreads();
    int base = blockIdx.x * EPB;
    for (int j = threadIdx.x; j < EPB; j += 256) atomicAdd(&h[col[base + j] >> 6], 1);
    __syncthreads();
    for (int i = threadIdx.x; i < NB; i += 256) H[i * NBLK + blockIdx.x] = h[i];
}

// ---------- phase 2: exclusive scan of H (NB*NBLK, bucket-major) ----------
__global__ __launch_bounds__(256) void scan1_kernel(int* H, int* __restrict__ bsum) {
    __shared__ int s[256];
    int i = blockIdx.x * 256 + threadIdx.x;
    int v = H[i];
    s[threadIdx.x] = v;
    __syncthreads();
    #pragma unroll
    for (int off = 1; off < 256; off <<= 1) {
        int t = (threadIdx.x >= off) ? s[threadIdx.x - off] : 0;
        __syncthreads();
        s[threadIdx.x] += t;
        __syncthreads();
    }
    H[i] = s[threadIdx.x] - v;                           // exclusive within bucket
    if (threadIdx.x == 255) bsum[blockIdx.x] = s[255];   // bucket total
}

__global__ __launch_bounds__(256) void scan2_kernel(const int* __restrict__ bsum,
                                                    int* __restrict__ boff) {
    __shared__ int s[256];
    __shared__ int carry;
    if (threadIdx.x == 0) carry = 0;
    __syncthreads();
    for (int c = 0; c < (NB + 255) / 256; ++c) {
        int i = c * 256 + threadIdx.x;
        int v = (i < NB) ? bsum[i] : 0;
        s[threadIdx.x] = v;
        __syncthreads();
        #pragma unroll
        for (int off = 1; off < 256; off <<= 1) {
            int t = (threadIdx.x >= off) ? s[threadIdx.x - off] : 0;
            __syncthreads();
            s[threadIdx.x] += t;
            __syncthreads();
        }
        if (i < NB) boff[i] = s[threadIdx.x] - v + carry;   // bucket start offsets
        __syncthreads();
        if (threadIdx.x == 0) carry += s[255];
        __syncthreads();
    }
}

__global__ __launch_bounds__(256) void scan3_kernel(int* H, const int* __restrict__ boff) {
    int i = blockIdx.x * 256 + threadIdx.x;   // grid NB; blockIdx.x == bucket
    H[i] += boff[blockIdx.x];
}

// ---------- phase 3: scatter records to bucket-contiguous; cursors in LDS ----------
__global__ __launch_bounds__(256) void bscatter_kernel(const int* __restrict__ row,
                                                       const int* __restrict__ col,
                                                       const float* __restrict__ ew,
                                                       const int* __restrict__ H,
                                                       int2* __restrict__ recsA) {
    __shared__ int cur[NB];
    for (int i = threadIdx.x; i < NB; i += 256) cur[i] = H[i * NBLK + blockIdx.x];
    __syncthreads();
    int base = blockIdx.x * EPB;
    for (int j = threadIdx.x; j < EPB; j += 256) {
        int e = base + j;
        int c = col[e];
        int pos = atomicAdd(&cur[c >> 6], 1);
        recsA[pos] = make_int2(row[e] | ((c & 63) << 17), __float_as_int(ew[e]));
    }
}

// ---------- phase 4: per-bucket counting sort -> per-node CSR; fused deg/dis/rowptr ----
// csr[pos] = (row, ew * dis[col]);  gather multiplies by dis[row] later.
__global__ __launch_bounds__(256) void bsort_kernel(const int2* __restrict__ recsA,
                                                    const int* __restrict__ boff,
                                                    float2* __restrict__ csr,
                                                    int* __restrict__ rowptr,
                                                    float* __restrict__ dis) {
    __shared__ int   cnt[64];
    __shared__ float degf[64];
    __shared__ int   cur[64];
    __shared__ float sdis[64];
    int b = blockIdx.x, tid = threadIdx.x;
    if (tid < 64) { cnt[tid] = 0; degf[tid] = 0.f; }
    __syncthreads();
    int s = boff[b], e = (b + 1 < NB) ? boff[b + 1] : N_EDGES;
    for (int j = s + tid; j < e; j += 256) {
        int2 r = recsA[j];
        int cl = (r.x >> 17) & 63;
        atomicAdd(&cnt[cl], 1);
        atomicAdd(&degf[cl], __int_as_float(r.y));
    }
    __syncthreads();
    if (tid < 64) {                      // wave 0 does the 64-wide scan
        int c = cnt[tid];
        int v = c;
        #pragma unroll
        for (int o = 1; o < 64; o <<= 1) {
            int t = __shfl_up(v, o, 64);
            if (tid >= o) v += t;
        }
        int excl = v - c;
        cur[tid] = excl;
        rowptr[b * 64 + tid] = s + excl;           // trailing nodes (cnt=0) give rowptr[N]=E
        float d = 1.0f / sqrtf(fmaxf(1.0f + degf[tid], 1e-30f));
        sdis[tid] = d;
        dis[b * 64 + tid] = d;
    }
    __syncthreads();
    for (int j = s + tid; j < e; j += 256) {
        int2 r = recsA[j];
        int cl = (r.x >> 17) & 63;
        int pos = s + atomicAdd(&cur[cl], 1);
        csr[pos] = make_float2(__int_as_float(r.x & 0x1FFFF),
                               __int_as_float(r.y) * sdis[cl]);
    }
}

// ---------- layer 1 GEMM: xl = x @ W1 ----------
__global__ __launch_bounds__(256) void gemm1_kernel(const float* __restrict__ x,
                                                    const float* __restrict__ W1,
                                                    float* __restrict__ xl) {
    __shared__ float sW[IN_DIM * HID];   // 32 KB
    __shared__ float sx[4][IN_DIM];
    int tid = threadIdx.x;
    const float4* W4  = (const float4*)W1;
    float4*       sW4 = (float4*)sW;
    #pragma unroll
    for (int i = 0; i < 8; ++i) sW4[tid + 256 * i] = W4[tid + 256 * i];
    int r0 = blockIdx.x * 4;
    const float4* x4  = (const float4*)(x + (size_t)r0 * IN_DIM);
    float4*       sx4 = (float4*)&sx[0][0];
    if (tid < 128) sx4[tid] = x4[tid];
    __syncthreads();
    int lr = tid >> 6, c = tid & 63;
    float acc = 0.f;
    #pragma unroll 8
    for (int k = 0; k < IN_DIM; ++k) acc += sx[lr][k] * sW[k * HID + c];
    xl[(size_t)(r0 + lr) * HID + c] = acc;
}

// ---------- gather aggregation (R2-proven): agg[n] = xl[n]*dis[n]^2 + sum_in csr ----------
// one wave per node; 4 quarters x 16 lanes x float4 = 4 edges in flight
__global__ __launch_bounds__(256) void gather_kernel(const float2* __restrict__ csr,
                                                     const int* __restrict__ rowptr,
                                                     const float* __restrict__ dis,
                                                     const float* __restrict__ xl,
                                                     float* __restrict__ agg) {
    int n    = (blockIdx.x * 256 + threadIdx.x) >> 6;   // grid 25000 exact
    int lane = threadIdx.x & 63;
    int q    = lane >> 4;
    int c0   = (lane & 15) << 2;
    int base = rowptr[n], end = rowptr[n + 1];
    float4 acc = make_float4(0.f, 0.f, 0.f, 0.f);
    if (q == 0) {
        float d  = dis[n];
        float d2 = d * d;
        float4 xs = *(const float4*)(xl + (size_t)n * HID + c0);
        acc = make_float4(xs.x * d2, xs.y * d2, xs.z * d2, xs.w * d2);
    }
    for (int j = base + q; j < end; j += 4) {
        float2 e = csr[j];
        int   r  = __float_as_int(e.x);
        float w  = dis[r] * e.y;
        float4 xv = *(const float4*)(xl + (size_t)r * HID + c0);
        acc.x += xv.x * w; acc.y += xv.y * w;
        acc.z += xv.z * w; acc.w += xv.w * w;
    }
    acc.x += __shfl_down(acc.x, 32, 64); acc.y += __shfl_down(acc.y, 32, 64);
    acc.z += __shfl_down(acc.z, 32, 64); acc.w += __shfl_down(acc.w, 32, 64);
    acc.x += __shfl_down(acc.x, 16, 64); acc.y += __shfl_down(acc.y, 16, 64);
    acc.z += __shfl_down(acc.z, 16, 64); acc.w += __shfl_down(acc.w, 16, 64);
    if (lane < 16) *(float4*)(agg + (size_t)n * HID + c0) = acc;
}

// ---------- layer 2 GEMM: xl2 = relu(agg1 + b1) @ W2 ----------
__global__ __launch_bounds__(256) void gemm2_kernel(const float* __restrict__ agg1,
                                                    const float* __restrict__ W2,
                                                    const float* __restrict__ b1,
                                                    float* __restrict__ xl2) {
    __shared__ float sW[HID * HID];
    __shared__ float sh[4][HID];
    int tid = threadIdx.x;
    const float4* W4  = (const float4*)W2;
    float4*       sW4 = (float4*)sW;
    #pragma unroll
    for (int i = 0; i < 4; ++i) sW4[tid + 256 * i] = W4[tid + 256 * i];
    int r0 = blockIdx.x * 4;
    int lr = tid >> 6, c = tid & 63;
    float v = agg1[(size_t)(r0 + lr) * HID + c] + b1[c];
    sh[lr][c] = v > 0.f ? v : 0.f;
    __syncthreads();
    float acc = 0.f;
    #pragma unroll 8
    for (int k = 0; k < HID; ++k) acc += sh[lr][k] * sW[k * HID + c];
    xl2[(size_t)(r0 + lr) * HID + c] = acc;
}

// ---------- pooling + head ----------
__global__ __launch_bounds__(256) void pool_head_kernel(const float* __restrict__ agg2,
                                                        const float* __restrict__ b2,
                                                        const int* __restrict__ batch,
                                                        const float* __restrict__ Wc,
                                                        const float* __restrict__ bc,
                                                        float* __restrict__ out) {
    int g = blockIdx.x;
    int lo = 0, hi = N_NODES;
    while (lo < hi) { int m = (lo + hi) >> 1; if (batch[m] < g) lo = m + 1; else hi = m; }
    int start = lo;
    hi = N_NODES;
    while (lo < hi) { int m = (lo + hi) >> 1; if (batch[m] < g + 1) lo = m + 1; else hi = m; }
    int end = lo;
    int w = threadIdx.x >> 6, lane = threadIdx.x & 63;
    float bb = b2[lane];
    float acc = 0.f;
    for (int i = start + w; i < end; i += 4) {
        float v = agg2[(size_t)i * HID + lane] + bb;
        acc += v > 0.f ? v : 0.f;
    }
    __shared__ float s[4][HID];
    s[w][lane] = acc;
    __syncthreads();
    if (w == 0) {
        float p = s[0][lane] + s[1][lane] + s[2][lane] + s[3][lane];
        float cntf = (float)(end - start);
        p = p / fmaxf(cntf, 1.0f) * Wc[lane];
        #pragma unroll
        for (int o = 32; o > 0; o >>= 1) p += __shfl_down(p, o, 64);
        if (lane == 0) out[g] = p + bc[0];
    }
}

extern "C" void kernel_launch(void* const* d_in, const int* in_sizes, int n_in,
                              void* d_out, int out_size, void* d_ws, size_t ws_size,
                              hipStream_t stream) {
    const float* x     = (const float*)d_in[0];
    const int*   ei    = (const int*)  d_in[1];
    const float* ew    = (const float*)d_in[2];
    const int*   batch = (const int*)  d_in[3];
    const float* W1    = (const float*)d_in[4];
    const float* b1    = (const float*)d_in[5];
    const float* W2    = (const float*)d_in[6];
    const float* b2    = (const float*)d_in[7];
    const float* Wc    = (const float*)d_in[8];
    const float* bc    = (const float*)d_in[9];
    float* out = (float*)d_out;

    const int* row = ei;
    const int* col = ei + N_EDGES;

    // workspace (~77.7 MB): bufA | bufB | csr | rowptr | dis | bsum | boff
    // recsA aliases bufA (dead before gemm1 writes bufA); H aliases bufB (dead before gather1)
    float*  bufA   = (float*)d_ws;                           // N*HID floats = 25.6 MB
    float*  bufB   = bufA + (size_t)N_NODES * HID;           // N*HID
    float2* csr    = (float2*)(bufB + (size_t)N_NODES * HID);// E float2
    int*    rowptr = (int*)(csr + N_EDGES);                  // N_PAD
    float*  dis    = (float*)(rowptr + N_PAD);               // N_PAD
    int*    bsum   = (int*)(dis + N_PAD);                    // 2048
    int*    boff   = bsum + 2048;                            // 2048
    int2*   recsA  = (int2*)bufA;                            // E int2 = 25.6 MB (== bufA size)
    int*    H      = (int*)bufB;                             // NB*NBLK ints = 1.6 MB

    bhist_kernel   <<<NBLK, 256, 0, stream>>>(col, H);
    scan1_kernel   <<<NB,   256, 0, stream>>>(H, bsum);
    scan2_kernel   <<<1,    256, 0, stream>>>(bsum, boff);
    scan3_kernel   <<<NB,   256, 0, stream>>>(H, boff);
    bscatter_kernel<<<NBLK, 256, 0, stream>>>(row, col, ew, H, recsA);
    bsort_kernel   <<<NB,   256, 0, stream>>>(recsA, boff, csr, rowptr, dis);
    gemm1_kernel   <<<N_NODES / 4, 256, 0, stream>>>(x, W1, bufA);
    gather_kernel  <<<N_NODES / 4, 256, 0, stream>>>(csr, rowptr, dis, bufA, bufB);
    gemm2_kernel   <<<N_NODES / 4, 256, 0, stream>>>(bufB, W2, b1, bufA);
    gather_kernel  <<<N_NODES / 4, 256, 0, stream>>>(csr, rowptr, dis, bufA, bufB);
    pool_head_kernel<<<N_GRAPHS, 256, 0, stream>>>(bufB, b2, batch, Wc, bc, out);
}

// Round 6
// 600.395 us; speedup vs baseline: 4.6660x; 1.0972x over previous
//
#include <hip/hip_runtime.h>

#define N_NODES 100000
#define N_PAD   100352        // 392*256
#define N_EDGES 3200000
#define IN_DIM  128
#define HID     64
#define N_GRAPHS 256
#define NB      392           // buckets of 256 dest nodes each
#define NBLK    256           // hist/scatter blocks
#define EPB     (N_EDGES / NBLK)   // 12500

// ---------- phase 1: per-block bucket histogram (LDS only, no global atomics) ----------
__global__ __launch_bounds__(256) void bhist_kernel(const int* __restrict__ col,
                                                    int* __restrict__ H) {
    __shared__ int h[NB];
    for (int i = threadIdx.x; i < NB; i += 256) h[i] = 0;
    __syncthreads();
    int base = blockIdx.x * EPB;
    for (int j = threadIdx.x; j < EPB; j += 256) atomicAdd(&h[col[base + j] >> 8], 1);
    __syncthreads();
    for (int i = threadIdx.x; i < NB; i += 256) H[i * NBLK + blockIdx.x] = h[i];
}

// ---------- phase 2: exclusive scan of H (NB*NBLK, bucket-major) ----------
__global__ __launch_bounds__(256) void scan1_kernel(int* H, int* __restrict__ bsum) {
    __shared__ int s[256];
    int i = blockIdx.x * 256 + threadIdx.x;   // blockIdx.x == bucket (NBLK==256)
    int v = H[i];
    s[threadIdx.x] = v;
    __syncthreads();
    #pragma unroll
    for (int off = 1; off < 256; off <<= 1) {
        int t = (threadIdx.x >= off) ? s[threadIdx.x - off] : 0;
        __syncthreads();
        s[threadIdx.x] += t;
        __syncthreads();
    }
    H[i] = s[threadIdx.x] - v;                           // exclusive within bucket
    if (threadIdx.x == 255) bsum[blockIdx.x] = s[255];   // bucket total
}

__global__ __launch_bounds__(256) void scan2_kernel(const int* __restrict__ bsum,
                                                    int* __restrict__ boff) {
    __shared__ int s[256];
    __shared__ int carry;
    if (threadIdx.x == 0) carry = 0;
    __syncthreads();
    for (int c = 0; c < (NB + 255) / 256; ++c) {
        int i = c * 256 + threadIdx.x;
        int v = (i < NB) ? bsum[i] : 0;
        s[threadIdx.x] = v;
        __syncthreads();
        #pragma unroll
        for (int off = 1; off < 256; off <<= 1) {
            int t = (threadIdx.x >= off) ? s[threadIdx.x - off] : 0;
            __syncthreads();
            s[threadIdx.x] += t;
            __syncthreads();
        }
        if (i < NB) boff[i] = s[threadIdx.x] - v + carry;   // bucket start offsets
        __syncthreads();
        if (threadIdx.x == 0) carry += s[255];
        __syncthreads();
    }
}

// ---------- phase 3: scatter records to bucket-contiguous; cursors in LDS ----------
// rec = (row | local<<17, ew); local = col & 255 (8 bits), row < 2^17
__global__ __launch_bounds__(256) void bscatter_kernel(const int* __restrict__ row,
                                                       const int* __restrict__ col,
                                                       const float* __restrict__ ew,
                                                       const int* __restrict__ H,
                                                       const int* __restrict__ boff,
                                                       int2* __restrict__ recsA) {
    __shared__ int cur[NB];
    for (int i = threadIdx.x; i < NB; i += 256)
        cur[i] = H[i * NBLK + blockIdx.x] + boff[i];      // fused scan3
    __syncthreads();
    int base = blockIdx.x * EPB;
    for (int j = threadIdx.x; j < EPB; j += 256) {
        int e = base + j;
        int c = col[e];
        int pos = atomicAdd(&cur[c >> 8], 1);
        recsA[pos] = make_int2(row[e] | ((c & 255) << 17), __float_as_int(ew[e]));
    }
}

// ---------- phase 4: per-bucket counting sort -> per-node CSR; fused deg/dis/rowptr ----
// csr[pos] = (row, ew * dis[col]);  gather multiplies by dis[row] later.
__global__ __launch_bounds__(256) void bsort_kernel(const int2* __restrict__ recsA,
                                                    const int* __restrict__ boff,
                                                    float2* __restrict__ csr,
                                                    int* __restrict__ rowptr,
                                                    float* __restrict__ dis) {
    __shared__ int   cnt[256];
    __shared__ float degf[256];
    __shared__ int   cur[256];
    __shared__ float sdis[256];
    __shared__ int   sscan[256];
    int b = blockIdx.x, tid = threadIdx.x;
    cnt[tid] = 0; degf[tid] = 0.f;
    __syncthreads();
    int s = boff[b], e = (b + 1 < NB) ? boff[b + 1] : N_EDGES;
    for (int j = s + tid; j < e; j += 256) {
        int2 r = recsA[j];
        int cl = (r.x >> 17) & 255;
        atomicAdd(&cnt[cl], 1);
        atomicAdd(&degf[cl], __int_as_float(r.y));
    }
    __syncthreads();
    int c = cnt[tid];
    sscan[tid] = c;
    __syncthreads();
    #pragma unroll
    for (int off = 1; off < 256; off <<= 1) {
        int t = (tid >= off) ? sscan[tid - off] : 0;
        __syncthreads();
        sscan[tid] += t;
        __syncthreads();
    }
    int excl = sscan[tid] - c;
    cur[tid] = excl;
    rowptr[b * 256 + tid] = s + excl;    // trailing zero-cnt nodes give rowptr[N]=E
    float d = 1.0f / sqrtf(fmaxf(1.0f + degf[tid], 1e-30f));
    sdis[tid] = d;
    dis[b * 256 + tid] = d;
    __syncthreads();
    for (int j = s + tid; j < e; j += 256) {
        int2 r = recsA[j];
        int cl = (r.x >> 17) & 255;
        int pos = s + atomicAdd(&cur[cl], 1);
        csr[pos] = make_float2(__int_as_float(r.x & 0x1FFFF),
                               __int_as_float(r.y) * sdis[cl]);
    }
}

// ---------- layer 1 GEMM: xl = x @ W1 ----------
__global__ __launch_bounds__(256) void gemm1_kernel(const float* __restrict__ x,
                                                    const float* __restrict__ W1,
                                                    float* __restrict__ xl) {
    __shared__ float sW[IN_DIM * HID];   // 32 KB
    __shared__ float sx[4][IN_DIM];
    int tid = threadIdx.x;
    const float4* W4  = (const float4*)W1;
    float4*       sW4 = (float4*)sW;
    #pragma unroll
    for (int i = 0; i < 8; ++i) sW4[tid + 256 * i] = W4[tid + 256 * i];
    int r0 = blockIdx.x * 4;
    const float4* x4  = (const float4*)(x + (size_t)r0 * IN_DIM);
    float4*       sx4 = (float4*)&sx[0][0];
    if (tid < 128) sx4[tid] = x4[tid];
    __syncthreads();
    int lr = tid >> 6, c = tid & 63;
    float acc = 0.f;
    #pragma unroll 8
    for (int k = 0; k < IN_DIM; ++k) acc += sx[lr][k] * sW[k * HID + c];
    xl[(size_t)(r0 + lr) * HID + c] = acc;
}

// ---------- fused gather1 + gemm2: xl2 = relu(gather(xl1) + b1) @ W2 ----------
// wave per node gathers its agg1 row into LDS, then block does the 64x64 GEMM.
__global__ __launch_bounds__(256) void gather_gemm2_kernel(
        const float2* __restrict__ csr, const int* __restrict__ rowptr,
        const float* __restrict__ dis, const float* __restrict__ xl,
        const float* __restrict__ W2, const float* __restrict__ b1,
        float* __restrict__ xl2) {
    __shared__ float sW[HID * HID];   // 16 KB
    __shared__ float sh[4][HID];
    __shared__ float sb1[HID];
    int tid = threadIdx.x;
    const float4* W4  = (const float4*)W2;
    float4*       sW4 = (float4*)sW;
    #pragma unroll
    for (int i = 0; i < 4; ++i) sW4[tid + 256 * i] = W4[tid + 256 * i];
    if (tid < HID) sb1[tid] = b1[tid];

    int r0   = blockIdx.x * 4;
    int wv   = tid >> 6;
    int n    = r0 + wv;
    int lane = tid & 63;
    int q    = lane >> 4;
    int c0   = (lane & 15) << 2;
    int base = rowptr[n], end = rowptr[n + 1];
    float4 acc = make_float4(0.f, 0.f, 0.f, 0.f);
    if (q == 0) {
        float d  = dis[n];
        float d2 = d * d;
        float4 xs = *(const float4*)(xl + (size_t)n * HID + c0);
        acc = make_float4(xs.x * d2, xs.y * d2, xs.z * d2, xs.w * d2);
    }
    int j = base + q;
    for (; j + 4 < end; j += 8) {                       // 2 edges per quarter in flight
        float2 e0 = csr[j];
        float2 e1 = csr[j + 4];
        int   ra = __float_as_int(e0.x), rb = __float_as_int(e1.x);
        float w0 = dis[ra] * e0.y,       w1 = dis[rb] * e1.y;
        float4 xa = *(const float4*)(xl + (size_t)ra * HID + c0);
        float4 xb = *(const float4*)(xl + (size_t)rb * HID + c0);
        acc.x += xa.x * w0 + xb.x * w1; acc.y += xa.y * w0 + xb.y * w1;
        acc.z += xa.z * w0 + xb.z * w1; acc.w += xa.w * w0 + xb.w * w1;
    }
    if (j < end) {
        float2 e0 = csr[j];
        int   ra = __float_as_int(e0.x);
        float w0 = dis[ra] * e0.y;
        float4 xa = *(const float4*)(xl + (size_t)ra * HID + c0);
        acc.x += xa.x * w0; acc.y += xa.y * w0;
        acc.z += xa.z * w0; acc.w += xa.w * w0;
    }
    acc.x += __shfl_down(acc.x, 32, 64); acc.y += __shfl_down(acc.y, 32, 64);
    acc.z += __shfl_down(acc.z, 32, 64); acc.w += __shfl_down(acc.w, 32, 64);
    acc.x += __shfl_down(acc.x, 16, 64); acc.y += __shfl_down(acc.y, 16, 64);
    acc.z += __shfl_down(acc.z, 16, 64); acc.w += __shfl_down(acc.w, 16, 64);
    if (lane < 16) *(float4*)(&sh[wv][c0]) = acc;
    __syncthreads();                                    // sW, sb1, sh all visible
    int lr = wv, cc = lane;
    float hv = fmaxf(sh[lr][cc] + sb1[cc], 0.f);        // relu(agg1 + b1)
    __syncthreads();
    sh[lr][cc] = hv;
    __syncthreads();
    float acc2 = 0.f;
    #pragma unroll 8
    for (int k = 0; k < HID; ++k) acc2 += sh[lr][k] * sW[k * HID + cc];
    xl2[(size_t)(r0 + lr) * HID + cc] = acc2;
}

// ---------- gather aggregation: agg[n] = xl[n]*dis[n]^2 + sum_in csr ----------
__global__ __launch_bounds__(256) void gather_kernel(const float2* __restrict__ csr,
                                                     const int* __restrict__ rowptr,
                                                     const float* __restrict__ dis,
                                                     const float* __restrict__ xl,
                                                     float* __restrict__ agg) {
    int n    = (blockIdx.x * 256 + threadIdx.x) >> 6;   // grid 25000 exact
    int lane = threadIdx.x & 63;
    int q    = lane >> 4;
    int c0   = (lane & 15) << 2;
    int base = rowptr[n], end = rowptr[n + 1];
    float4 acc = make_float4(0.f, 0.f, 0.f, 0.f);
    if (q == 0) {
        float d  = dis[n];
        float d2 = d * d;
        float4 xs = *(const float4*)(xl + (size_t)n * HID + c0);
        acc = make_float4(xs.x * d2, xs.y * d2, xs.z * d2, xs.w * d2);
    }
    int j = base + q;
    for (; j + 4 < end; j += 8) {
        float2 e0 = csr[j];
        float2 e1 = csr[j + 4];
        int   ra = __float_as_int(e0.x), rb = __float_as_int(e1.x);
        float w0 = dis[ra] * e0.y,       w1 = dis[rb] * e1.y;
        float4 xa = *(const float4*)(xl + (size_t)ra * HID + c0);
        float4 xb = *(const float4*)(xl + (size_t)rb * HID + c0);
        acc.x += xa.x * w0 + xb.x * w1; acc.y += xa.y * w0 + xb.y * w1;
        acc.z += xa.z * w0 + xb.z * w1; acc.w += xa.w * w0 + xb.w * w1;
    }
    if (j < end) {
        float2 e0 = csr[j];
        int   ra = __float_as_int(e0.x);
        float w0 = dis[ra] * e0.y;
        float4 xa = *(const float4*)(xl + (size_t)ra * HID + c0);
        acc.x += xa.x * w0; acc.y += xa.y * w0;
        acc.z += xa.z * w0; acc.w += xa.w * w0;
    }
    acc.x += __shfl_down(acc.x, 32, 64); acc.y += __shfl_down(acc.y, 32, 64);
    acc.z += __shfl_down(acc.z, 32, 64); acc.w += __shfl_down(acc.w, 32, 64);
    acc.x += __shfl_down(acc.x, 16, 64); acc.y += __shfl_down(acc.y, 16, 64);
    acc.z += __shfl_down(acc.z, 16, 64); acc.w += __shfl_down(acc.w, 16, 64);
    if (lane < 16) *(float4*)(agg + (size_t)n * HID + c0) = acc;
}

// ---------- pooling + head ----------
__global__ __launch_bounds__(256) void pool_head_kernel(const float* __restrict__ agg2,
                                                        const float* __restrict__ b2,
                                                        const int* __restrict__ batch,
                                                        const float* __restrict__ Wc,
                                                        const float* __restrict__ bc,
                                                        float* __restrict__ out) {
    int g = blockIdx.x;
    int lo = 0, hi = N_NODES;
    while (lo < hi) { int m = (lo + hi) >> 1; if (batch[m] < g) lo = m + 1; else hi = m; }
    int start = lo;
    hi = N_NODES;
    while (lo < hi) { int m = (lo + hi) >> 1; if (batch[m] < g + 1) lo = m + 1; else hi = m; }
    int end = lo;
    int w = threadIdx.x >> 6, lane = threadIdx.x & 63;
    float bb = b2[lane];
    float acc = 0.f;
    for (int i = start + w; i < end; i += 4) {
        float v = agg2[(size_t)i * HID + lane] + bb;
        acc += v > 0.f ? v : 0.f;
    }
    __shared__ float s[4][HID];
    s[w][lane] = acc;
    __syncthreads();
    if (w == 0) {
        float p = s[0][lane] + s[1][lane] + s[2][lane] + s[3][lane];
        float cntf = (float)(end - start);
        p = p / fmaxf(cntf, 1.0f) * Wc[lane];
        #pragma unroll
        for (int o = 32; o > 0; o >>= 1) p += __shfl_down(p, o, 64);
        if (lane == 0) out[g] = p + bc[0];
    }
}

extern "C" void kernel_launch(void* const* d_in, const int* in_sizes, int n_in,
                              void* d_out, int out_size, void* d_ws, size_t ws_size,
                              hipStream_t stream) {
    const float* x     = (const float*)d_in[0];
    const int*   ei    = (const int*)  d_in[1];
    const float* ew    = (const float*)d_in[2];
    const int*   batch = (const int*)  d_in[3];
    const float* W1    = (const float*)d_in[4];
    const float* b1    = (const float*)d_in[5];
    const float* W2    = (const float*)d_in[6];
    const float* b2    = (const float*)d_in[7];
    const float* Wc    = (const float*)d_in[8];
    const float* bc    = (const float*)d_in[9];
    float* out = (float*)d_out;

    const int* row = ei;
    const int* col = ei + N_EDGES;

    // workspace (~77.6 MB): bufA | bufB | csr | rowptr | dis | bsum | boff
    // recsA aliases bufB (dead before fused kernel writes xl2 there);
    // H aliases csr (dead before bsort writes csr).
    float*  bufA   = (float*)d_ws;                            // N*HID floats (xl1, later agg2)
    float*  bufB   = bufA + (size_t)N_NODES * HID;            // N*HID (recsA, later xl2)
    float2* csr    = (float2*)(bufB + (size_t)N_NODES * HID); // E float2
    int*    rowptr = (int*)(csr + N_EDGES);                   // N_PAD
    float*  dis    = (float*)(rowptr + N_PAD);                // N_PAD
    int*    bsum   = (int*)(dis + N_PAD);                     // 512
    int*    boff   = bsum + 512;                              // 512
    int2*   recsA  = (int2*)bufB;                             // E int2 == bufB size
    int*    H      = (int*)csr;                               // NB*NBLK ints = 401 KB

    bhist_kernel    <<<NBLK, 256, 0, stream>>>(col, H);
    scan1_kernel    <<<NB,   256, 0, stream>>>(H, bsum);
    scan2_kernel    <<<1,    256, 0, stream>>>(bsum, boff);
    bscatter_kernel <<<NBLK, 256, 0, stream>>>(row, col, ew, H, boff, recsA);
    bsort_kernel    <<<NB,   256, 0, stream>>>(recsA, boff, csr, rowptr, dis);
    gemm1_kernel    <<<N_NODES / 4, 256, 0, stream>>>(x, W1, bufA);
    gather_gemm2_kernel<<<N_NODES / 4, 256, 0, stream>>>(csr, rowptr, dis, bufA, W2, b1, bufB);
    gather_kernel   <<<N_NODES / 4, 256, 0, stream>>>(csr, rowptr, dis, bufB, bufA);
    pool_head_kernel<<<N_GRAPHS, 256, 0, stream>>>(bufA, b2, batch, Wc, bc, out);
}

// Round 7
// 548.848 us; speedup vs baseline: 5.1042x; 1.0939x over previous
//
#include <hip/hip_runtime.h>

#define N_NODES 100000
#define N_PAD   100352        // 392*256
#define N_EDGES 3200000
#define IN_DIM  128
#define HID     64
#define N_GRAPHS 256
#define NB      392           // buckets of 256 dest nodes each
#define NBLK    256           // hist/scatter blocks
#define EPB     (N_EDGES / NBLK)   // 12500

typedef unsigned short ushort_t;
typedef unsigned int   uint_t;

// bf16 helpers: storage-only compression of the gathered operand
__device__ __forceinline__ ushort_t f2bf(float v) {          // round-to-nearest-even
    uint_t b = __float_as_uint(v);
    b += 0x7fffu + ((b >> 16) & 1u);
    return (ushort_t)(b >> 16);
}
__device__ __forceinline__ float4 ld_bf16x4(const ushort_t* p) {   // 8B load -> 4 floats
    uint2 u = *(const uint2*)p;
    float4 f;
    f.x = __uint_as_float((u.x & 0xffffu) << 16);
    f.y = __uint_as_float(u.x & 0xffff0000u);
    f.z = __uint_as_float((u.y & 0xffffu) << 16);
    f.w = __uint_as_float(u.y & 0xffff0000u);
    return f;
}

// ---------- phase 1: per-block bucket histogram (LDS only, no global atomics) ----------
__global__ __launch_bounds__(256) void bhist_kernel(const int* __restrict__ col,
                                                    int* __restrict__ H) {
    __shared__ int h[NB];
    for (int i = threadIdx.x; i < NB; i += 256) h[i] = 0;
    __syncthreads();
    int base = blockIdx.x * EPB;
    for (int j = threadIdx.x; j < EPB; j += 256) atomicAdd(&h[col[base + j] >> 8], 1);
    __syncthreads();
    for (int i = threadIdx.x; i < NB; i += 256) H[i * NBLK + blockIdx.x] = h[i];
}

// ---------- phase 2: exclusive scan of H (NB*NBLK, bucket-major) ----------
__global__ __launch_bounds__(256) void scan1_kernel(int* H, int* __restrict__ bsum) {
    __shared__ int s[256];
    int i = blockIdx.x * 256 + threadIdx.x;   // blockIdx.x == bucket (NBLK==256)
    int v = H[i];
    s[threadIdx.x] = v;
    __syncthreads();
    #pragma unroll
    for (int off = 1; off < 256; off <<= 1) {
        int t = (threadIdx.x >= off) ? s[threadIdx.x - off] : 0;
        __syncthreads();
        s[threadIdx.x] += t;
        __syncthreads();
    }
    H[i] = s[threadIdx.x] - v;                           // exclusive within bucket
    if (threadIdx.x == 255) bsum[blockIdx.x] = s[255];   // bucket total
}

__global__ __launch_bounds__(256) void scan2_kernel(const int* __restrict__ bsum,
                                                    int* __restrict__ boff) {
    __shared__ int s[256];
    __shared__ int carry;
    if (threadIdx.x == 0) carry = 0;
    __syncthreads();
    for (int c = 0; c < (NB + 255) / 256; ++c) {
        int i = c * 256 + threadIdx.x;
        int v = (i < NB) ? bsum[i] : 0;
        s[threadIdx.x] = v;
        __syncthreads();
        #pragma unroll
        for (int off = 1; off < 256; off <<= 1) {
            int t = (threadIdx.x >= off) ? s[threadIdx.x - off] : 0;
            __syncthreads();
            s[threadIdx.x] += t;
            __syncthreads();
        }
        if (i < NB) boff[i] = s[threadIdx.x] - v + carry;   // bucket start offsets
        __syncthreads();
        if (threadIdx.x == 0) carry += s[255];
        __syncthreads();
    }
}

// ---------- phase 3: scatter records to bucket-contiguous; cursors in LDS ----------
// rec = (row | local<<17, ew); local = col & 255 (8 bits), row < 2^17
__global__ __launch_bounds__(256) void bscatter_kernel(const int* __restrict__ row,
                                                       const int* __restrict__ col,
                                                       const float* __restrict__ ew,
                                                       const int* __restrict__ H,
                                                       const int* __restrict__ boff,
                                                       int2* __restrict__ recsA) {
    __shared__ int cur[NB];
    for (int i = threadIdx.x; i < NB; i += 256)
        cur[i] = H[i * NBLK + blockIdx.x] + boff[i];      // fused scan3
    __syncthreads();
    int base = blockIdx.x * EPB;
    for (int j = threadIdx.x; j < EPB; j += 256) {
        int e = base + j;
        int c = col[e];
        int pos = atomicAdd(&cur[c >> 8], 1);
        recsA[pos] = make_int2(row[e] | ((c & 255) << 17), __float_as_int(ew[e]));
    }
}

// ---------- phase 4: per-bucket counting sort -> per-node CSR; fused deg/dis/rowptr ----
// csr[pos] = (row, ew * dis[col]);  gather multiplies by dis[row] later.
__global__ __launch_bounds__(256) void bsort_kernel(const int2* __restrict__ recsA,
                                                    const int* __restrict__ boff,
                                                    float2* __restrict__ csr,
                                                    int* __restrict__ rowptr,
                                                    float* __restrict__ dis) {
    __shared__ int   cnt[256];
    __shared__ float degf[256];
    __shared__ int   cur[256];
    __shared__ float sdis[256];
    __shared__ int   sscan[256];
    int b = blockIdx.x, tid = threadIdx.x;
    cnt[tid] = 0; degf[tid] = 0.f;
    __syncthreads();
    int s = boff[b], e = (b + 1 < NB) ? boff[b + 1] : N_EDGES;
    for (int j = s + tid; j < e; j += 256) {
        int2 r = recsA[j];
        int cl = (r.x >> 17) & 255;
        atomicAdd(&cnt[cl], 1);
        atomicAdd(&degf[cl], __int_as_float(r.y));
    }
    __syncthreads();
    int c = cnt[tid];
    sscan[tid] = c;
    __syncthreads();
    #pragma unroll
    for (int off = 1; off < 256; off <<= 1) {
        int t = (tid >= off) ? sscan[tid - off] : 0;
        __syncthreads();
        sscan[tid] += t;
        __syncthreads();
    }
    int excl = sscan[tid] - c;
    cur[tid] = excl;
    rowptr[b * 256 + tid] = s + excl;    // trailing zero-cnt nodes give rowptr[N]=E
    float d = 1.0f / sqrtf(fmaxf(1.0f + degf[tid], 1e-30f));
    sdis[tid] = d;
    dis[b * 256 + tid] = d;
    __syncthreads();
    for (int j = s + tid; j < e; j += 256) {
        int2 r = recsA[j];
        int cl = (r.x >> 17) & 255;
        int pos = s + atomicAdd(&cur[cl], 1);
        csr[pos] = make_float2(__int_as_float(r.x & 0x1FFFF),
                               __int_as_float(r.y) * sdis[cl]);
    }
}

// ---------- layer 1 GEMM: xl = x @ W1 (bf16 output) ----------
__global__ __launch_bounds__(256) void gemm1_kernel(const float* __restrict__ x,
                                                    const float* __restrict__ W1,
                                                    ushort_t* __restrict__ xl) {
    __shared__ float sW[IN_DIM * HID];   // 32 KB
    __shared__ float sx[4][IN_DIM];
    int tid = threadIdx.x;
    const float4* W4  = (const float4*)W1;
    float4*       sW4 = (float4*)sW;
    #pragma unroll
    for (int i = 0; i < 8; ++i) sW4[tid + 256 * i] = W4[tid + 256 * i];
    int r0 = blockIdx.x * 4;
    const float4* x4  = (const float4*)(x + (size_t)r0 * IN_DIM);
    float4*       sx4 = (float4*)&sx[0][0];
    if (tid < 128) sx4[tid] = x4[tid];
    __syncthreads();
    int lr = tid >> 6, c = tid & 63;
    float acc = 0.f;
    #pragma unroll 8
    for (int k = 0; k < IN_DIM; ++k) acc += sx[lr][k] * sW[k * HID + c];
    xl[(size_t)(r0 + lr) * HID + c] = f2bf(acc);
}

// ---------- fused gather1 + gemm2: xl2 = relu(gather(xl1) + b1) @ W2 (bf16 out) ----------
__global__ __launch_bounds__(256) void gather_gemm2_kernel(
        const float2* __restrict__ csr, const int* __restrict__ rowptr,
        const float* __restrict__ dis, const ushort_t* __restrict__ xl,
        const float* __restrict__ W2, const float* __restrict__ b1,
        ushort_t* __restrict__ xl2) {
    __shared__ float sW[HID * HID];   // 16 KB
    __shared__ float sh[4][HID];
    __shared__ float sb1[HID];
    int tid = threadIdx.x;
    const float4* W4  = (const float4*)W2;
    float4*       sW4 = (float4*)sW;
    #pragma unroll
    for (int i = 0; i < 4; ++i) sW4[tid + 256 * i] = W4[tid + 256 * i];
    if (tid < HID) sb1[tid] = b1[tid];

    int r0   = blockIdx.x * 4;
    int wv   = tid >> 6;
    int n    = r0 + wv;
    int lane = tid & 63;
    int q    = lane >> 4;
    int c0   = (lane & 15) << 2;
    int base = rowptr[n], end = rowptr[n + 1];
    float4 acc = make_float4(0.f, 0.f, 0.f, 0.f);
    if (q == 0) {
        float d  = dis[n];
        float d2 = d * d;
        float4 xs = ld_bf16x4(xl + (size_t)n * HID + c0);
        acc = make_float4(xs.x * d2, xs.y * d2, xs.z * d2, xs.w * d2);
    }
    int j = base + q;
    for (; j + 4 < end; j += 8) {                       // 2 edges per quarter in flight
        float2 e0 = csr[j];
        float2 e1 = csr[j + 4];
        int   ra = __float_as_int(e0.x), rb = __float_as_int(e1.x);
        float w0 = dis[ra] * e0.y,       w1 = dis[rb] * e1.y;
        float4 xa = ld_bf16x4(xl + (size_t)ra * HID + c0);
        float4 xb = ld_bf16x4(xl + (size_t)rb * HID + c0);
        acc.x += xa.x * w0 + xb.x * w1; acc.y += xa.y * w0 + xb.y * w1;
        acc.z += xa.z * w0 + xb.z * w1; acc.w += xa.w * w0 + xb.w * w1;
    }
    if (j < end) {
        float2 e0 = csr[j];
        int   ra = __float_as_int(e0.x);
        float w0 = dis[ra] * e0.y;
        float4 xa = ld_bf16x4(xl + (size_t)ra * HID + c0);
        acc.x += xa.x * w0; acc.y += xa.y * w0;
        acc.z += xa.z * w0; acc.w += xa.w * w0;
    }
    acc.x += __shfl_down(acc.x, 32, 64); acc.y += __shfl_down(acc.y, 32, 64);
    acc.z += __shfl_down(acc.z, 32, 64); acc.w += __shfl_down(acc.w, 32, 64);
    acc.x += __shfl_down(acc.x, 16, 64); acc.y += __shfl_down(acc.y, 16, 64);
    acc.z += __shfl_down(acc.z, 16, 64); acc.w += __shfl_down(acc.w, 16, 64);
    if (lane < 16) *(float4*)(&sh[wv][c0]) = acc;
    __syncthreads();                                    // sW, sb1, sh all visible
    int lr = wv, cc = lane;
    float hv = fmaxf(sh[lr][cc] + sb1[cc], 0.f);        // relu(agg1 + b1)
    __syncthreads();
    sh[lr][cc] = hv;
    __syncthreads();
    float acc2 = 0.f;
    #pragma unroll 8
    for (int k = 0; k < HID; ++k) acc2 += sh[lr][k] * sW[k * HID + cc];
    xl2[(size_t)(r0 + lr) * HID + cc] = f2bf(acc2);
}

// ---------- gather aggregation: agg[n] = xl[n]*dis[n]^2 + sum_in csr (fp32 out) ----------
__global__ __launch_bounds__(256) void gather_kernel(const float2* __restrict__ csr,
                                                     const int* __restrict__ rowptr,
                                                     const float* __restrict__ dis,
                                                     const ushort_t* __restrict__ xl,
                                                     float* __restrict__ agg) {
    int n    = (blockIdx.x * 256 + threadIdx.x) >> 6;   // grid 25000 exact
    int lane = threadIdx.x & 63;
    int q    = lane >> 4;
    int c0   = (lane & 15) << 2;
    int base = rowptr[n], end = rowptr[n + 1];
    float4 acc = make_float4(0.f, 0.f, 0.f, 0.f);
    if (q == 0) {
        float d  = dis[n];
        float d2 = d * d;
        float4 xs = ld_bf16x4(xl + (size_t)n * HID + c0);
        acc = make_float4(xs.x * d2, xs.y * d2, xs.z * d2, xs.w * d2);
    }
    int j = base + q;
    for (; j + 4 < end; j += 8) {
        float2 e0 = csr[j];
        float2 e1 = csr[j + 4];
        int   ra = __float_as_int(e0.x), rb = __float_as_int(e1.x);
        float w0 = dis[ra] * e0.y,       w1 = dis[rb] * e1.y;
        float4 xa = ld_bf16x4(xl + (size_t)ra * HID + c0);
        float4 xb = ld_bf16x4(xl + (size_t)rb * HID + c0);
        acc.x += xa.x * w0 + xb.x * w1; acc.y += xa.y * w0 + xb.y * w1;
        acc.z += xa.z * w0 + xb.z * w1; acc.w += xa.w * w0 + xb.w * w1;
    }
    if (j < end) {
        float2 e0 = csr[j];
        int   ra = __float_as_int(e0.x);
        float w0 = dis[ra] * e0.y;
        float4 xa = ld_bf16x4(xl + (size_t)ra * HID + c0);
        acc.x += xa.x * w0; acc.y += xa.y * w0;
        acc.z += xa.z * w0; acc.w += xa.w * w0;
    }
    acc.x += __shfl_down(acc.x, 32, 64); acc.y += __shfl_down(acc.y, 32, 64);
    acc.z += __shfl_down(acc.z, 32, 64); acc.w += __shfl_down(acc.w, 32, 64);
    acc.x += __shfl_down(acc.x, 16, 64); acc.y += __shfl_down(acc.y, 16, 64);
    acc.z += __shfl_down(acc.z, 16, 64); acc.w += __shfl_down(acc.w, 16, 64);
    if (lane < 16) *(float4*)(agg + (size_t)n * HID + c0) = acc;
}

// ---------- pooling + head ----------
__global__ __launch_bounds__(256) void pool_head_kernel(const float* __restrict__ agg2,
                                                        const float* __restrict__ b2,
                                                        const int* __restrict__ batch,
                                                        const float* __restrict__ Wc,
                                                        const float* __restrict__ bc,
                                                        float* __restrict__ out) {
    int g = blockIdx.x;
    int lo = 0, hi = N_NODES;
    while (lo < hi) { int m = (lo + hi) >> 1; if (batch[m] < g) lo = m + 1; else hi = m; }
    int start = lo;
    hi = N_NODES;
    while (lo < hi) { int m = (lo + hi) >> 1; if (batch[m] < g + 1) lo = m + 1; else hi = m; }
    int end = lo;
    int w = threadIdx.x >> 6, lane = threadIdx.x & 63;
    float bb = b2[lane];
    float acc = 0.f;
    for (int i = start + w; i < end; i += 4) {
        float v = agg2[(size_t)i * HID + lane] + bb;
        acc += v > 0.f ? v : 0.f;
    }
    __shared__ float s[4][HID];
    s[w][lane] = acc;
    __syncthreads();
    if (w == 0) {
        float p = s[0][lane] + s[1][lane] + s[2][lane] + s[3][lane];
        float cntf = (float)(end - start);
        p = p / fmaxf(cntf, 1.0f) * Wc[lane];
        #pragma unroll
        for (int o = 32; o > 0; o >>= 1) p += __shfl_down(p, o, 64);
        if (lane == 0) out[g] = p + bc[0];
    }
}

extern "C" void kernel_launch(void* const* d_in, const int* in_sizes, int n_in,
                              void* d_out, int out_size, void* d_ws, size_t ws_size,
                              hipStream_t stream) {
    const float* x     = (const float*)d_in[0];
    const int*   ei    = (const int*)  d_in[1];
    const float* ew    = (const float*)d_in[2];
    const int*   batch = (const int*)  d_in[3];
    const float* W1    = (const float*)d_in[4];
    const float* b1    = (const float*)d_in[5];
    const float* W2    = (const float*)d_in[6];
    const float* b2    = (const float*)d_in[7];
    const float* Wc    = (const float*)d_in[8];
    const float* bc    = (const float*)d_in[9];
    float* out = (float*)d_out;

    const int* row = ei;
    const int* col = ei + N_EDGES;

    // workspace (~77.6 MB): bufA(fp32) | xlA(bf16) | xlB(bf16) | csr | rowptr | dis | bsum | boff
    // recsA aliases bufA (dead before gather2 writes agg2 there); H aliases csr.
    float*    bufA   = (float*)d_ws;                             // N*HID fp32 (recsA, later agg2)
    ushort_t* xlA    = (ushort_t*)(bufA + (size_t)N_NODES * HID);// N*HID bf16
    ushort_t* xlB    = xlA + (size_t)N_NODES * HID;              // N*HID bf16
    float2*   csr    = (float2*)(xlB + (size_t)N_NODES * HID);   // E float2
    int*      rowptr = (int*)(csr + N_EDGES);                    // N_PAD
    float*    dis    = (float*)(rowptr + N_PAD);                 // N_PAD
    int*      bsum   = (int*)(dis + N_PAD);                      // 512
    int*      boff   = bsum + 512;                               // 512
    int2*     recsA  = (int2*)bufA;                              // E int2 == bufA size
    int*      H      = (int*)csr;                                // NB*NBLK ints = 401 KB

    bhist_kernel    <<<NBLK, 256, 0, stream>>>(col, H);
    scan1_kernel    <<<NB,   256, 0, stream>>>(H, bsum);
    scan2_kernel    <<<1,    256, 0, stream>>>(bsum, boff);
    bscatter_kernel <<<NBLK, 256, 0, stream>>>(row, col, ew, H, boff, recsA);
    bsort_kernel    <<<NB,   256, 0, stream>>>(recsA, boff, csr, rowptr, dis);
    gemm1_kernel    <<<N_NODES / 4, 256, 0, stream>>>(x, W1, xlA);
    gather_gemm2_kernel<<<N_NODES / 4, 256, 0, stream>>>(csr, rowptr, dis, xlA, W2, b1, xlB);
    gather_kernel   <<<N_NODES / 4, 256, 0, stream>>>(csr, rowptr, dis, xlB, bufA);
    pool_head_kernel<<<N_GRAPHS, 256, 0, stream>>>(bufA, b2, batch, Wc, bc, out);
}

// Round 8
// 545.345 us; speedup vs baseline: 5.1370x; 1.0064x over previous
//
#include <hip/hip_runtime.h>

#define N_NODES 100000
#define N_PAD   100352        // 392*256
#define N_EDGES 3200000
#define IN_DIM  128
#define HID     64
#define N_GRAPHS 256
#define NB      392           // buckets of 256 dest nodes each
#define NBLK    256           // hist/scatter blocks
#define EPB     (N_EDGES / NBLK)   // 12500

typedef unsigned short ushort_t;
typedef unsigned int   uint_t;

// bf16 helpers: storage-only compression of the gathered operand
__device__ __forceinline__ ushort_t f2bf(float v) {          // round-to-nearest-even
    uint_t b = __float_as_uint(v);
    b += 0x7fffu + ((b >> 16) & 1u);
    return (ushort_t)(b >> 16);
}
__device__ __forceinline__ void bf2f2(uint_t u, float& lo, float& hi) {
    lo = __uint_as_float(u << 16);
    hi = __uint_as_float(u & 0xffff0000u);
}
// 16B load -> 8 floats
__device__ __forceinline__ void ld_bf16x8(const ushort_t* p, float4& a, float4& b) {
    uint4 u = *(const uint4*)p;
    bf2f2(u.x, a.x, a.y); bf2f2(u.y, a.z, a.w);
    bf2f2(u.z, b.x, b.y); bf2f2(u.w, b.z, b.w);
}

// ---------- phase 1: per-block bucket histogram (LDS only, no global atomics) ----------
__global__ __launch_bounds__(256) void bhist_kernel(const int* __restrict__ col,
                                                    int* __restrict__ H) {
    __shared__ int h[NB];
    for (int i = threadIdx.x; i < NB; i += 256) h[i] = 0;
    __syncthreads();
    int base = blockIdx.x * EPB;
    for (int j = threadIdx.x; j < EPB; j += 256) atomicAdd(&h[col[base + j] >> 8], 1);
    __syncthreads();
    for (int i = threadIdx.x; i < NB; i += 256) H[i * NBLK + blockIdx.x] = h[i];
}

// ---------- phase 2: exclusive scan of H (NB*NBLK, bucket-major) ----------
__global__ __launch_bounds__(256) void scan1_kernel(int* H, int* __restrict__ bsum) {
    __shared__ int s[256];
    int i = blockIdx.x * 256 + threadIdx.x;   // blockIdx.x == bucket (NBLK==256)
    int v = H[i];
    s[threadIdx.x] = v;
    __syncthreads();
    #pragma unroll
    for (int off = 1; off < 256; off <<= 1) {
        int t = (threadIdx.x >= off) ? s[threadIdx.x - off] : 0;
        __syncthreads();
        s[threadIdx.x] += t;
        __syncthreads();
    }
    H[i] = s[threadIdx.x] - v;                           // exclusive within bucket
    if (threadIdx.x == 255) bsum[blockIdx.x] = s[255];   // bucket total
}

__global__ __launch_bounds__(256) void scan2_kernel(const int* __restrict__ bsum,
                                                    int* __restrict__ boff) {
    __shared__ int s[256];
    __shared__ int carry;
    if (threadIdx.x == 0) carry = 0;
    __syncthreads();
    for (int c = 0; c < (NB + 255) / 256; ++c) {
        int i = c * 256 + threadIdx.x;
        int v = (i < NB) ? bsum[i] : 0;
        s[threadIdx.x] = v;
        __syncthreads();
        #pragma unroll
        for (int off = 1; off < 256; off <<= 1) {
            int t = (threadIdx.x >= off) ? s[threadIdx.x - off] : 0;
            __syncthreads();
            s[threadIdx.x] += t;
            __syncthreads();
        }
        if (i < NB) boff[i] = s[threadIdx.x] - v + carry;   // bucket start offsets
        __syncthreads();
        if (threadIdx.x == 0) carry += s[255];
        __syncthreads();
    }
}

// ---------- phase 3: scatter records to bucket-contiguous; cursors in LDS ----------
// rec = (row | local<<17, ew); local = col & 255 (8 bits), row < 2^17
__global__ __launch_bounds__(256) void bscatter_kernel(const int* __restrict__ row,
                                                       const int* __restrict__ col,
                                                       const float* __restrict__ ew,
                                                       const int* __restrict__ H,
                                                       const int* __restrict__ boff,
                                                       int2* __restrict__ recsA) {
    __shared__ int cur[NB];
    for (int i = threadIdx.x; i < NB; i += 256)
        cur[i] = H[i * NBLK + blockIdx.x] + boff[i];      // fused scan3
    __syncthreads();
    int base = blockIdx.x * EPB;
    for (int j = threadIdx.x; j < EPB; j += 256) {
        int e = base + j;
        int c = col[e];
        int pos = atomicAdd(&cur[c >> 8], 1);
        recsA[pos] = make_int2(row[e] | ((c & 255) << 17), __float_as_int(ew[e]));
    }
}

// ---------- phase 3.5: deg/dis per bucket from recsA (LDS accumulation) ----------
__global__ __launch_bounds__(256) void degdis_kernel(const int2* __restrict__ recsA,
                                                     const int* __restrict__ boff,
                                                     float* __restrict__ dis) {
    __shared__ float degf[256];
    int b = blockIdx.x, tid = threadIdx.x;
    degf[tid] = 0.f;
    __syncthreads();
    int s = boff[b], e = (b + 1 < NB) ? boff[b + 1] : N_EDGES;
    for (int j = s + tid; j < e; j += 256) {
        int2 r = recsA[j];
        atomicAdd(&degf[(r.x >> 17) & 255], __int_as_float(r.y));
    }
    __syncthreads();
    dis[b * 256 + tid] = 1.0f / sqrtf(fmaxf(1.0f + degf[tid], 1e-30f));
}

// ---------- phase 4: per-bucket counting sort -> per-node CSR; FULL weight folded ----
// csr[pos] = (row, dis[row] * ew * dis[col])
__global__ __launch_bounds__(256) void bsort_kernel(const int2* __restrict__ recsA,
                                                    const int* __restrict__ boff,
                                                    const float* __restrict__ dis,
                                                    float2* __restrict__ csr,
                                                    int* __restrict__ rowptr) {
    __shared__ int   cnt[256];
    __shared__ int   cur[256];
    __shared__ float sdis[256];
    __shared__ int   sscan[256];
    int b = blockIdx.x, tid = threadIdx.x;
    cnt[tid] = 0;
    sdis[tid] = dis[b * 256 + tid];
    __syncthreads();
    int s = boff[b], e = (b + 1 < NB) ? boff[b + 1] : N_EDGES;
    for (int j = s + tid; j < e; j += 256) {
        int2 r = recsA[j];
        atomicAdd(&cnt[(r.x >> 17) & 255], 1);
    }
    __syncthreads();
    int c = cnt[tid];
    sscan[tid] = c;
    __syncthreads();
    #pragma unroll
    for (int off = 1; off < 256; off <<= 1) {
        int t = (tid >= off) ? sscan[tid - off] : 0;
        __syncthreads();
        sscan[tid] += t;
        __syncthreads();
    }
    int excl = sscan[tid] - c;
    cur[tid] = excl;
    rowptr[b * 256 + tid] = s + excl;    // trailing zero-cnt nodes give rowptr[N]=E
    __syncthreads();
    for (int j = s + tid; j < e; j += 256) {
        int2 r = recsA[j];
        int cl = (r.x >> 17) & 255;
        int rr = r.x & 0x1FFFF;
        int pos = s + atomicAdd(&cur[cl], 1);
        csr[pos] = make_float2(__int_as_float(rr),
                               dis[rr] * __int_as_float(r.y) * sdis[cl]);
    }
}

// ---------- layer 1 GEMM: xl = x @ W1 (bf16 output) ----------
__global__ __launch_bounds__(256) void gemm1_kernel(const float* __restrict__ x,
                                                    const float* __restrict__ W1,
                                                    ushort_t* __restrict__ xl) {
    __shared__ float sW[IN_DIM * HID];   // 32 KB
    __shared__ float sx[4][IN_DIM];
    int tid = threadIdx.x;
    const float4* W4  = (const float4*)W1;
    float4*       sW4 = (float4*)sW;
    #pragma unroll
    for (int i = 0; i < 8; ++i) sW4[tid + 256 * i] = W4[tid + 256 * i];
    int r0 = blockIdx.x * 4;
    const float4* x4  = (const float4*)(x + (size_t)r0 * IN_DIM);
    float4*       sx4 = (float4*)&sx[0][0];
    if (tid < 128) sx4[tid] = x4[tid];
    __syncthreads();
    int lr = tid >> 6, c = tid & 63;
    float acc = 0.f;
    #pragma unroll 8
    for (int k = 0; k < IN_DIM; ++k) acc += sx[lr][k] * sW[k * HID + c];
    xl[(size_t)(r0 + lr) * HID + c] = f2bf(acc);
}

// ---------- gather core: 8-lane groups, 16B loads, 2 edges in flight/group ----------
// returns per-lane partials for channels [gl*8, gl*8+8) reduced across groups
// (lanes 0..7 hold final result)
__device__ __forceinline__ void gather_row(const float2* __restrict__ csr,
                                           const ushort_t* __restrict__ xl,
                                           int base, int end, int n, float d2,
                                           int g, int gl, int c0,
                                           float4& a0, float4& a1) {
    a0 = make_float4(0.f, 0.f, 0.f, 0.f);
    a1 = make_float4(0.f, 0.f, 0.f, 0.f);
    if (g == 0) {
        float4 s0, s1;
        ld_bf16x8(xl + (size_t)n * HID + c0, s0, s1);
        a0.x = s0.x * d2; a0.y = s0.y * d2; a0.z = s0.z * d2; a0.w = s0.w * d2;
        a1.x = s1.x * d2; a1.y = s1.y * d2; a1.z = s1.z * d2; a1.w = s1.w * d2;
    }
    int j = base + g;
    for (; j + 8 < end; j += 16) {
        float2 e0 = csr[j];
        float2 e1 = csr[j + 8];
        int ra = __float_as_int(e0.x), rb = __float_as_int(e1.x);
        float w0 = e0.y, w1 = e1.y;
        float4 xa0, xa1, xb0, xb1;
        ld_bf16x8(xl + (size_t)ra * HID + c0, xa0, xa1);
        ld_bf16x8(xl + (size_t)rb * HID + c0, xb0, xb1);
        a0.x += xa0.x * w0 + xb0.x * w1; a0.y += xa0.y * w0 + xb0.y * w1;
        a0.z += xa0.z * w0 + xb0.z * w1; a0.w += xa0.w * w0 + xb0.w * w1;
        a1.x += xa1.x * w0 + xb1.x * w1; a1.y += xa1.y * w0 + xb1.y * w1;
        a1.z += xa1.z * w0 + xb1.z * w1; a1.w += xa1.w * w0 + xb1.w * w1;
    }
    if (j < end) {
        float2 e0 = csr[j];
        int ra = __float_as_int(e0.x);
        float w0 = e0.y;
        float4 xa0, xa1;
        ld_bf16x8(xl + (size_t)ra * HID + c0, xa0, xa1);
        a0.x += xa0.x * w0; a0.y += xa0.y * w0; a0.z += xa0.z * w0; a0.w += xa0.w * w0;
        a1.x += xa1.x * w0; a1.y += xa1.y * w0; a1.z += xa1.z * w0; a1.w += xa1.w * w0;
    }
    #pragma unroll
    for (int o = 32; o >= 8; o >>= 1) {
        a0.x += __shfl_down(a0.x, o, 64); a0.y += __shfl_down(a0.y, o, 64);
        a0.z += __shfl_down(a0.z, o, 64); a0.w += __shfl_down(a0.w, o, 64);
        a1.x += __shfl_down(a1.x, o, 64); a1.y += __shfl_down(a1.y, o, 64);
        a1.z += __shfl_down(a1.z, o, 64); a1.w += __shfl_down(a1.w, o, 64);
    }
}

// ---------- fused gather1 + gemm2: xl2 = relu(gather(xl1) + b1) @ W2 (bf16 out) ----------
__global__ __launch_bounds__(256) void gather_gemm2_kernel(
        const float2* __restrict__ csr, const int* __restrict__ rowptr,
        const float* __restrict__ dis, const ushort_t* __restrict__ xl,
        const float* __restrict__ W2, const float* __restrict__ b1,
        ushort_t* __restrict__ xl2) {
    __shared__ float sW[HID * HID];   // 16 KB
    __shared__ float sh[4][HID];
    __shared__ float sb1[HID];
    int tid = threadIdx.x;
    const float4* W4  = (const float4*)W2;
    float4*       sW4 = (float4*)sW;
    #pragma unroll
    for (int i = 0; i < 4; ++i) sW4[tid + 256 * i] = W4[tid + 256 * i];
    if (tid < HID) sb1[tid] = b1[tid];

    int r0   = blockIdx.x * 4;
    int wv   = tid >> 6;
    int n    = r0 + wv;
    int lane = tid & 63;
    int g    = lane >> 3;
    int gl   = lane & 7;
    int c0   = gl << 3;
    int base = rowptr[n], end = rowptr[n + 1];
    float d  = dis[n];
    float4 a0, a1;
    gather_row(csr, xl, base, end, n, d * d, g, gl, c0, a0, a1);
    if (lane < 8) {
        *(float4*)(&sh[wv][c0])     = a0;
        *(float4*)(&sh[wv][c0 + 4]) = a1;
    }
    __syncthreads();                                    // sW, sb1, sh all visible
    int lr = wv, cc = lane;
    float hv = fmaxf(sh[lr][cc] + sb1[cc], 0.f);        // relu(agg1 + b1)
    __syncthreads();
    sh[lr][cc] = hv;
    __syncthreads();
    float acc2 = 0.f;
    #pragma unroll 8
    for (int k = 0; k < HID; ++k) acc2 += sh[lr][k] * sW[k * HID + cc];
    xl2[(size_t)(r0 + lr) * HID + cc] = f2bf(acc2);
}

// ---------- gather aggregation: agg[n] = xl[n]*dis[n]^2 + sum_in csr (fp32 out) ----------
__global__ __launch_bounds__(256) void gather_kernel(const float2* __restrict__ csr,
                                                     const int* __restrict__ rowptr,
                                                     const float* __restrict__ dis,
                                                     const ushort_t* __restrict__ xl,
                                                     float* __restrict__ agg) {
    int tid  = threadIdx.x;
    int n    = (blockIdx.x * 256 + tid) >> 6;           // grid 25000 exact
    int lane = tid & 63;
    int g    = lane >> 3;
    int gl   = lane & 7;
    int c0   = gl << 3;
    int base = rowptr[n], end = rowptr[n + 1];
    float d  = dis[n];
    float4 a0, a1;
    gather_row(csr, xl, base, end, n, d * d, g, gl, c0, a0, a1);
    if (lane < 8) {
        *(float4*)(agg + (size_t)n * HID + c0)     = a0;
        *(float4*)(agg + (size_t)n * HID + c0 + 4) = a1;
    }
}

// ---------- pooling + head ----------
__global__ __launch_bounds__(256) void pool_head_kernel(const float* __restrict__ agg2,
                                                        const float* __restrict__ b2,
                                                        const int* __restrict__ batch,
                                                        const float* __restrict__ Wc,
                                                        const float* __restrict__ bc,
                                                        float* __restrict__ out) {
    int g = blockIdx.x;
    int lo = 0, hi = N_NODES;
    while (lo < hi) { int m = (lo + hi) >> 1; if (batch[m] < g) lo = m + 1; else hi = m; }
    int start = lo;
    hi = N_NODES;
    while (lo < hi) { int m = (lo + hi) >> 1; if (batch[m] < g + 1) lo = m + 1; else hi = m; }
    int end = lo;
    int w = threadIdx.x >> 6, lane = threadIdx.x & 63;
    float bb = b2[lane];
    float acc = 0.f;
    for (int i = start + w; i < end; i += 4) {
        float v = agg2[(size_t)i * HID + lane] + bb;
        acc += v > 0.f ? v : 0.f;
    }
    __shared__ float s[4][HID];
    s[w][lane] = acc;
    __syncthreads();
    if (w == 0) {
        float p = s[0][lane] + s[1][lane] + s[2][lane] + s[3][lane];
        float cntf = (float)(end - start);
        p = p / fmaxf(cntf, 1.0f) * Wc[lane];
        #pragma unroll
        for (int o = 32; o > 0; o >>= 1) p += __shfl_down(p, o, 64);
        if (lane == 0) out[g] = p + bc[0];
    }
}

extern "C" void kernel_launch(void* const* d_in, const int* in_sizes, int n_in,
                              void* d_out, int out_size, void* d_ws, size_t ws_size,
                              hipStream_t stream) {
    const float* x     = (const float*)d_in[0];
    const int*   ei    = (const int*)  d_in[1];
    const float* ew    = (const float*)d_in[2];
    const int*   batch = (const int*)  d_in[3];
    const float* W1    = (const float*)d_in[4];
    const float* b1    = (const float*)d_in[5];
    const float* W2    = (const float*)d_in[6];
    const float* b2    = (const float*)d_in[7];
    const float* Wc    = (const float*)d_in[8];
    const float* bc    = (const float*)d_in[9];
    float* out = (float*)d_out;

    const int* row = ei;
    const int* col = ei + N_EDGES;

    // workspace (~77.6 MB): bufA(fp32) | xlA(bf16) | xlB(bf16) | csr | rowptr | dis | bsum | boff
    // recsA aliases bufA (dead before gather2 writes agg2 there); H aliases csr.
    float*    bufA   = (float*)d_ws;                             // N*HID fp32 (recsA, later agg2)
    ushort_t* xlA    = (ushort_t*)(bufA + (size_t)N_NODES * HID);// N*HID bf16
    ushort_t* xlB    = xlA + (size_t)N_NODES * HID;              // N*HID bf16
    float2*   csr    = (float2*)(xlB + (size_t)N_NODES * HID);   // E float2
    int*      rowptr = (int*)(csr + N_EDGES);                    // N_PAD
    float*    dis    = (float*)(rowptr + N_PAD);                 // N_PAD
    int*      bsum   = (int*)(dis + N_PAD);                      // 512
    int*      boff   = bsum + 512;                               // 512
    int2*     recsA  = (int2*)bufA;                              // E int2 == bufA size
    int*      H      = (int*)csr;                                // NB*NBLK ints = 401 KB

    bhist_kernel    <<<NBLK, 256, 0, stream>>>(col, H);
    scan1_kernel    <<<NB,   256, 0, stream>>>(H, bsum);
    scan2_kernel    <<<1,    256, 0, stream>>>(bsum, boff);
    bscatter_kernel <<<NBLK, 256, 0, stream>>>(row, col, ew, H, boff, recsA);
    degdis_kernel   <<<NB,   256, 0, stream>>>(recsA, boff, dis);
    bsort_kernel    <<<NB,   256, 0, stream>>>(recsA, boff, dis, csr, rowptr);
    gemm1_kernel    <<<N_NODES / 4, 256, 0, stream>>>(x, W1, xlA);
    gather_gemm2_kernel<<<N_NODES / 4, 256, 0, stream>>>(csr, rowptr, dis, xlA, W2, b1, xlB);
    gather_kernel   <<<N_NODES / 4, 256, 0, stream>>>(csr, rowptr, dis, xlB, bufA);
    pool_head_kernel<<<N_GRAPHS, 256, 0, stream>>>(bufA, b2, batch, Wc, bc, out);
}